// Round 5
// baseline (780.785 us; speedup 1.0000x reference)
//
#include <hip/hip_runtime.h>
#include <math.h>

#define B_ 64
#define T_ 1024
#define D_ 256
#define U_ 256

typedef _Float16 h2_t __attribute__((ext_vector_type(2)));
typedef _Float16 h8_t __attribute__((ext_vector_type(8)));

// ---------------------------------------------------------------------------
// Kernel 1: proj = inputs @ W_xh + b_h  (UNCHANGED this round)
// ---------------------------------------------------------------------------
#define BM 64
#define BN 64
#define BK 16

__global__ __launch_bounds__(256, 2)
void proj_gemm(const float* __restrict__ A,
               const float* __restrict__ Bm,
               const float* __restrict__ bias,
               float* __restrict__ C) {
    __shared__ float As[BK][BM];
    __shared__ float Bs[BK][BN];

    const int m0 = blockIdx.x * BM;
    const int n0 = blockIdx.y * BN;
    const int tid = (int)threadIdx.x;
    const int tx = tid & 15;
    const int ty = tid >> 4;

    const int ar  = tid >> 2;
    const int akq = tid & 3;
    const int bk  = tid >> 4;
    const int bnq = tid & 15;

    float acc[4][4] = {};

    for (int k0 = 0; k0 < D_; k0 += BK) {
        float4 av = *(const float4*)&A[(size_t)(m0 + ar) * D_ + k0 + akq * 4];
        float4 bv = *(const float4*)&Bm[(size_t)(k0 + bk) * U_ + n0 + bnq * 4];
        __syncthreads();
        As[akq * 4 + 0][ar] = av.x;
        As[akq * 4 + 1][ar] = av.y;
        As[akq * 4 + 2][ar] = av.z;
        As[akq * 4 + 3][ar] = av.w;
        *(float4*)&Bs[bk][bnq * 4] = bv;
        __syncthreads();
        #pragma unroll
        for (int kk = 0; kk < BK; ++kk) {
            float4 a = *(const float4*)&As[kk][ty * 4];
            float4 b = *(const float4*)&Bs[kk][tx * 4];
            acc[0][0] = fmaf(a.x, b.x, acc[0][0]);
            acc[0][1] = fmaf(a.x, b.y, acc[0][1]);
            acc[0][2] = fmaf(a.x, b.z, acc[0][2]);
            acc[0][3] = fmaf(a.x, b.w, acc[0][3]);
            acc[1][0] = fmaf(a.y, b.x, acc[1][0]);
            acc[1][1] = fmaf(a.y, b.y, acc[1][1]);
            acc[1][2] = fmaf(a.y, b.z, acc[1][2]);
            acc[1][3] = fmaf(a.y, b.w, acc[1][3]);
            acc[2][0] = fmaf(a.z, b.x, acc[2][0]);
            acc[2][1] = fmaf(a.z, b.y, acc[2][1]);
            acc[2][2] = fmaf(a.z, b.z, acc[2][2]);
            acc[2][3] = fmaf(a.z, b.w, acc[2][3]);
            acc[3][0] = fmaf(a.w, b.x, acc[3][0]);
            acc[3][1] = fmaf(a.w, b.y, acc[3][1]);
            acc[3][2] = fmaf(a.w, b.z, acc[3][2]);
            acc[3][3] = fmaf(a.w, b.w, acc[3][3]);
        }
    }

    const float4 bb = *(const float4*)&bias[n0 + tx * 4];
    #pragma unroll
    for (int i = 0; i < 4; ++i) {
        const int row = m0 + ty * 4 + i;
        float4 o;
        o.x = acc[i][0] + bb.x;
        o.y = acc[i][1] + bb.y;
        o.z = acc[i][2] + bb.z;
        o.w = acc[i][3] + bb.w;
        *(float4*)&C[(size_t)row * U_ + n0 + tx * 4] = o;
    }
}

__device__ __forceinline__ float fast_tanh(float x) {
    float a = fminf(fabsf(x) * 2.0f, 20.0f);
    float e = __expf(a);
    float t = 1.0f - 2.0f * __builtin_amdgcn_rcpf(e + 1.0f);
    return copysignf(t, x);
}

// ---------------------------------------------------------------------------
// Kernel 2: recurrence, ONE barrier per step.
// 512 threads = 8 waves. Wave g owns k-slice AND u-slice [32g, 32g+32):
// the h-values wave g's matvec needs (indexed by k) are exactly the ones it
// finalizes itself -> h never crosses waves; only partials do (via LDS,
// double-buffered part[2]). Per step:
//   matvec (4 b128 hbuf broadcast reads + 64 dot2) -> part[t&1] b128 write
//   -> barrier -> each wave finalizes its own 32 u (8 b32 part reads,
//   2-way dup = free) + xw + tanh -> private hbuf row (b16; next matvec
//   needs only lgkmcnt, NO second barrier).
// xW chunked 16 steps into LDS (loads at chunk start, ds_write mid-chunk ->
// vmcnt drain amortized); h stored to global delayed one step so the store
// retires before the next barrier's vmcnt(0) drain.
// ---------------------------------------------------------------------------
#define NT2_ 512
#define CH_  16

__global__ __launch_bounds__(NT2_) __attribute__((amdgpu_waves_per_eu(2, 2)))
void rnn_scan(const float* __restrict__ W_hh,   // [U_, U_]
              float* __restrict__ out) {        // [B_, T_, U_]: xW in, h out
    const int b    = (int)blockIdx.x;
    const int tid  = (int)threadIdx.x;
    const int g    = tid >> 6;        // wave id: k-slice AND u-slice owner
    const int lane = tid & 63;
    const int l31  = lane & 31;
    const int u0   = 4 * lane;        // matvec: 4 consecutive u per lane
    const int k0   = 32 * g;          // k-slice base
    const int uf   = 32 * g + l31;    // finalize u (lanes l and l+32 dup)

    __shared__ float    xbuf[2][CH_][U_];  // xw chunks (fp32)
    __shared__ float    part[2][8][U_];    // per-k-group partials, dbuffered
    __shared__ _Float16 hbuf[8][32];       // per-wave private h (f16)

    // W_hh slice -> f16 pair regs (identical to R4: VGPR-resident at 64 regs)
    h2_t wreg[16][4];
    #pragma unroll
    for (int kk = 0; kk < 16; ++kk) {
        const float4 ra = *(const float4*)&W_hh[(size_t)(k0 + 2 * kk) * U_ + u0];
        const float4 rb = *(const float4*)&W_hh[(size_t)(k0 + 2 * kk + 1) * U_ + u0];
        wreg[kk][0] = h2_t{(_Float16)ra.x, (_Float16)rb.x};
        wreg[kk][1] = h2_t{(_Float16)ra.y, (_Float16)rb.y};
        wreg[kk][2] = h2_t{(_Float16)ra.z, (_Float16)rb.z};
        wreg[kk][3] = h2_t{(_Float16)ra.w, (_Float16)rb.w};
    }

    float* gx = out + (size_t)b * T_ * U_;   // xw in / h out (in place)

    // h0 = 0; stage chunk 0 into xbuf[0]
    if (lane < 32) hbuf[g][l31] = (_Float16)0.f;
    {
        float4 v0 = *(const float4*)&gx[8 * tid];
        float4 v1 = *(const float4*)&gx[8 * tid + 4];
        float* bf = &xbuf[0][0][0];
        *(float4*)&bf[8 * tid]     = v0;
        *(float4*)&bf[8 * tid + 4] = v1;
    }
    __syncthreads();

    float4 xv0, xv1;          // next-chunk staging registers
    float  h_prev = 0.0f;     // delayed global store

    for (int t = 0; t < T_; ++t) {
        const int j   = t & 15;          // step within chunk
        const int cpp = (t >> 4) & 1;    // chunk parity
        const int pp  = t & 1;           // partials parity

        // delayed h store: issued right after the previous barrier region,
        // has a full step to retire before the next vmcnt(0) drain.
        if (t > 0 && lane < 32) gx[(size_t)(t - 1) * U_ + uf] = h_prev;

        // chunk pipeline: loads at j==0, LDS write at j==8 (8 steps of cover)
        if (j == 0 && t + 16 < T_) {
            const float* src = gx + (size_t)(t + 16) * U_;
            xv0 = *(const float4*)&src[8 * tid];
            xv1 = *(const float4*)&src[8 * tid + 4];
        }
        if (j == 8 && t + 8 < T_) {
            float* dst = &xbuf[1 - cpp][0][0];
            *(float4*)&dst[8 * tid]     = xv0;
            *(float4*)&dst[8 * tid + 4] = xv1;
        }

        // ---- matvec over own k-slice (hbuf row is wave-private: only
        // lgkmcnt orders last step's write before these reads)
        float4 acc = make_float4(0.f, 0.f, 0.f, 0.f);
        const h8_t* h8 = (const h8_t*)&hbuf[g][0];   // wave-uniform addr
        #pragma unroll
        for (int i = 0; i < 4; ++i) {
            h8_t hv = h8[i];                         // b128 broadcast
            #pragma unroll
            for (int cc = 0; cc < 4; ++cc) {
                h2_t hp = h2_t{hv[2 * cc], hv[2 * cc + 1]};
                const int kk = 4 * i + cc;
                acc.x = __builtin_amdgcn_fdot2(hp, wreg[kk][0], acc.x, false);
                acc.y = __builtin_amdgcn_fdot2(hp, wreg[kk][1], acc.y, false);
                acc.z = __builtin_amdgcn_fdot2(hp, wreg[kk][2], acc.z, false);
                acc.w = __builtin_amdgcn_fdot2(hp, wreg[kk][3], acc.w, false);
            }
        }
        *(float4*)&part[pp][g][u0] = acc;    // b128, 2 lanes/bank = free

        __syncthreads();                     // the ONLY barrier per step

        // ---- finalize own 32 u (both lane-halves compute identically)
        float s = xbuf[cpp][j][uf];          // b32, 2-way dup = free
        #pragma unroll
        for (int i = 0; i < 8; ++i)
            s += part[pp][i][uf];            // b32, bank=lane&31, 2-way dup
        const float hn = fast_tanh(s);
        if (lane < 32) hbuf[g][l31] = (_Float16)hn;  // private row, no barrier
        h_prev = hn;
    }

    // final store (t = T_-1)
    if (lane < 32) gx[(size_t)(T_ - 1) * U_ + uf] = h_prev;
}

// ---------------------------------------------------------------------------
extern "C" void kernel_launch(void* const* d_in, const int* in_sizes, int n_in,
                              void* d_out, int out_size, void* d_ws, size_t ws_size,
                              hipStream_t stream) {
    const float* inputs = (const float*)d_in[0];   // [B, T, D]
    const float* W_xh   = (const float*)d_in[1];   // [D, U]
    const float* W_hh   = (const float*)d_in[2];   // [U, U]
    const float* b_h    = (const float*)d_in[3];   // [U]
    float* out = (float*)d_out;                    // [B, T, U]

    const int M = B_ * T_;                         // 65536
    dim3 g1(M / BM, U_ / BN);                      // (1024, 4)
    proj_gemm<<<g1, 256, 0, stream>>>(inputs, W_xh, b_h, out);
    rnn_scan<<<B_, NT2_, 0, stream>>>(W_hh, out);
}

// Round 7
// 767.184 us; speedup vs baseline: 1.0177x; 1.0177x over previous
//
#include <hip/hip_runtime.h>
#include <math.h>

#define B_ 64
#define T_ 1024
#define D_ 256
#define U_ 256

typedef _Float16 h2_t  __attribute__((ext_vector_type(2)));
typedef _Float16 f16x4 __attribute__((ext_vector_type(4)));
typedef _Float16 f16x8 __attribute__((ext_vector_type(8)));
typedef float    f32x4 __attribute__((ext_vector_type(4)));

// ---------------------------------------------------------------------------
// Kernel 1: proj = inputs @ W_xh + b_h via MFMA f16 (f32 accumulate).
// Block 256 thr / 4 waves, tile M=64 N=64, K-chunks of 32.
// As[m][k], BsT[n][k] in LDS (f16, rows padded to 40 to spread banks).
// R6 BUG FIX: B staging now covers all 32 k per chunk (8 per thread, one
// f16x8 store) — R6 only wrote k 0..15, leaving half of BsT uninitialized.
// A-frag: A[m=lane&15][k=8*(lane>>4)+j] (contig b128 from As row).
// B-frag: B[k][n=lane&15], k=8*(lane>>4)+j (contig b128 from BsT row).
// C/D: col=lane&15, row=4*(lane>>4)+reg  [m89 mapping, dtype-independent].
// ---------------------------------------------------------------------------
#define PBM 64
#define PBN 64
#define PLD 40

__global__ __launch_bounds__(256, 2)
void proj_gemm(const float* __restrict__ A,      // [M, D_]
               const float* __restrict__ Bm,     // [D_, U_]
               const float* __restrict__ bias,   // [U_]
               float* __restrict__ C) {          // [M, U_]
    __shared__ _Float16 As[PBM][PLD];
    __shared__ _Float16 BsT[PBN][PLD];

    const int tid  = (int)threadIdx.x;
    const int w    = tid >> 6;
    const int lane = tid & 63;
    const int m16  = lane & 15;
    const int q    = lane >> 4;

    const int m0 = blockIdx.x * PBM;
    const int n0 = blockIdx.y * PBN;

    const int ar  = tid >> 3;     // A rows 0..31 (+32 for 2nd half)
    const int acq = tid & 7;      // A k-quad 0..7
    const int bn  = tid & 63;     // B col 0..63
    const int bko = (tid >> 6) * 8;  // B k-offset base: 0,8,16,24

    f32x4 acc[4] = {};

    for (int k0 = 0; k0 < D_; k0 += 32) {
        // global loads (coalesced)
        const float4 a0 = *(const float4*)&A[(size_t)(m0 + ar) * D_ + k0 + 4 * acq];
        const float4 a1 = *(const float4*)&A[(size_t)(m0 + ar + 32) * D_ + k0 + 4 * acq];
        float bv[8];
        #pragma unroll
        for (int c = 0; c < 8; ++c)
            bv[c] = Bm[(size_t)(k0 + bko + c) * U_ + n0 + bn];

        __syncthreads();   // prev chunk's frag reads done before overwrite

        f16x4 av0 = {(_Float16)a0.x, (_Float16)a0.y, (_Float16)a0.z, (_Float16)a0.w};
        f16x4 av1 = {(_Float16)a1.x, (_Float16)a1.y, (_Float16)a1.z, (_Float16)a1.w};
        f16x8 bh;
        #pragma unroll
        for (int c = 0; c < 8; ++c) bh[c] = (_Float16)bv[c];
        *(f16x4*)&As[ar][4 * acq]      = av0;
        *(f16x4*)&As[ar + 32][4 * acq] = av1;
        *(f16x8*)&BsT[bn][bko]         = bh;

        __syncthreads();   // tiles visible

        const f16x8 af = *(const f16x8*)&As[16 * w + m16][8 * q];
        #pragma unroll
        for (int nt = 0; nt < 4; ++nt) {
            const f16x8 bf = *(const f16x8*)&BsT[16 * nt + m16][8 * q];
            acc[nt] = __builtin_amdgcn_mfma_f32_16x16x32_f16(af, bf, acc[nt], 0, 0, 0);
        }
    }

    // epilogue: C[m0+16w+4q+r][n0+16nt+m16] = acc[nt][r] + bias
    const int row0 = m0 + 16 * w + 4 * q;
    #pragma unroll
    for (int nt = 0; nt < 4; ++nt) {
        const float bb = bias[n0 + 16 * nt + m16];
        #pragma unroll
        for (int r = 0; r < 4; ++r)
            C[(size_t)(row0 + r) * U_ + n0 + 16 * nt + m16] = acc[nt][r] + bb;
    }
}

__device__ __forceinline__ float fast_tanh(float x) {
    float a = fminf(fabsf(x) * 2.0f, 20.0f);
    float e = __expf(a);
    float t = 1.0f - 2.0f * __builtin_amdgcn_rcpf(e + 1.0f);
    return copysignf(t, x);
}

// ---------------------------------------------------------------------------
// Kernel 2: recurrence (unchanged from R6 — audited clean; R6's failure was
// the proj_gemm staging bug). 8 waves; wave g owns k-slice AND u-slice
// [32g,32g+32). h never touches LDS: finalize packs f16 pairs, distributes
// in-register via v_readlane -> 16 wave-uniform ints feeding v_dot2_f32_f16.
// Only partials cross waves (LDS, double-buffered). ONE raw s_barrier/step
// (lgkmcnt only — no vmcnt drain; global h-store + chunk prefetch retire
// asynchronously). Finalize split across dup lane-halves + shfl_xor(32).
// ---------------------------------------------------------------------------
#define NT2_ 512
#define CH_  16

__global__ __launch_bounds__(NT2_) __attribute__((amdgpu_waves_per_eu(2, 2)))
void rnn_scan(const float* __restrict__ W_hh,   // [U_, U_]
              float* __restrict__ out) {        // [B_, T_, U_]: xW in, h out
    const int b    = (int)blockIdx.x;
    const int tid  = (int)threadIdx.x;
    const int g    = tid >> 6;
    const int lane = tid & 63;
    const int l31  = lane & 31;
    const int u0   = 4 * lane;
    const int k0   = 32 * g;
    const int uf   = 32 * g + l31;
    const int half = lane >> 5;          // finalize partial-split

    __shared__ float xbuf[2][CH_][U_];   // xw chunks (fp32)
    __shared__ float part[2][8][U_];     // partials, double-buffered

    // W_hh slice -> f16 pair regs (64 VGPRs; resident per R4/R5 VGPR=88)
    h2_t wreg[16][4];
    #pragma unroll
    for (int kk = 0; kk < 16; ++kk) {
        const float4 ra = *(const float4*)&W_hh[(size_t)(k0 + 2 * kk) * U_ + u0];
        const float4 rb = *(const float4*)&W_hh[(size_t)(k0 + 2 * kk + 1) * U_ + u0];
        wreg[kk][0] = h2_t{(_Float16)ra.x, (_Float16)rb.x};
        wreg[kk][1] = h2_t{(_Float16)ra.y, (_Float16)rb.y};
        wreg[kk][2] = h2_t{(_Float16)ra.z, (_Float16)rb.z};
        wreg[kk][3] = h2_t{(_Float16)ra.w, (_Float16)rb.w};
    }

    // wave-uniform h state: hs[i] = packed (h[32g+2i], h[32g+2i+1]) f16x2
    int hs[16];
    #pragma unroll
    for (int i = 0; i < 16; ++i) hs[i] = 0;

    float* gx = out + (size_t)b * T_ * U_;

    // stage chunk 0
    {
        float4 v0 = *(const float4*)&gx[8 * tid];
        float4 v1 = *(const float4*)&gx[8 * tid + 4];
        float* bf = &xbuf[0][0][0];
        *(float4*)&bf[8 * tid]     = v0;
        *(float4*)&bf[8 * tid + 4] = v1;
    }
    __syncthreads();

    float4 xv0, xv1;
    for (int t = 0; t < T_; ++t) {
        const int j   = t & 15;
        const int cpp = (t >> 4) & 1;
        const int pp  = t & 1;

        // early xw read: latency hidden under matvec issue
        const float xwv = xbuf[cpp][j][uf];

        // chunk pipeline: global loads at j==0, LDS stage at j==8
        if (j == 0 && t + 16 < T_) {
            const float* src = gx + (size_t)(t + 16) * U_;
            xv0 = *(const float4*)&src[8 * tid];
            xv1 = *(const float4*)&src[8 * tid + 4];
        }
        if (j == 8 && t + 8 < T_) {
            float* dst = &xbuf[1 - cpp][0][0];
            *(float4*)&dst[8 * tid]     = xv0;
            *(float4*)&dst[8 * tid + 4] = xv1;
        }

        // ---- matvec: 64 dot2, h from wave-uniform hs (NO LDS)
        float4 acc = make_float4(0.f, 0.f, 0.f, 0.f);
        #pragma unroll
        for (int i = 0; i < 16; ++i) {
            const h2_t hp = __builtin_bit_cast(h2_t, hs[i]);
            acc.x = __builtin_amdgcn_fdot2(hp, wreg[i][0], acc.x, false);
            acc.y = __builtin_amdgcn_fdot2(hp, wreg[i][1], acc.y, false);
            acc.z = __builtin_amdgcn_fdot2(hp, wreg[i][2], acc.z, false);
            acc.w = __builtin_amdgcn_fdot2(hp, wreg[i][3], acc.w, false);
        }
        *(float4*)&part[pp][g][u0] = acc;    // b128, 2-way dup free

        // raw barrier: order LDS only; vmcnt NOT drained
        __asm__ __volatile__("s_waitcnt lgkmcnt(0)\n\ts_barrier" ::: "memory");

        // ---- finalize own u: halves sum 4 partials each, combine via xor32
        float s = half ? 0.0f : xwv;
        const int q0 = 4 * half;
        s += part[pp][q0 + 0][uf];
        s += part[pp][q0 + 1][uf];
        s += part[pp][q0 + 2][uf];
        s += part[pp][q0 + 3][uf];
        s += __shfl_xor(s, 32, 64);
        const float hn = fast_tanh(s);

        if (lane < 32) gx[(size_t)t * U_ + uf] = hn;   // retires async (no drain)

        // pack pairs on even lanes, broadcast via readlane
        const float hnb  = __shfl_down(hn, 1, 64);
        const int packed = __builtin_bit_cast(int,
                               __builtin_amdgcn_cvt_pkrtz(hn, hnb));
        #pragma unroll
        for (int i = 0; i < 16; ++i)
            hs[i] = __builtin_amdgcn_readlane(packed, 2 * i);
    }
}

// ---------------------------------------------------------------------------
extern "C" void kernel_launch(void* const* d_in, const int* in_sizes, int n_in,
                              void* d_out, int out_size, void* d_ws, size_t ws_size,
                              hipStream_t stream) {
    const float* inputs = (const float*)d_in[0];   // [B, T, D]
    const float* W_xh   = (const float*)d_in[1];   // [D, U]
    const float* W_hh   = (const float*)d_in[2];   // [U, U]
    const float* b_h    = (const float*)d_in[3];   // [U]
    float* out = (float*)d_out;                    // [B, T, U]

    const int M = B_ * T_;                         // 65536
    dim3 g1(M / PBM, U_ / PBN);                    // (1024, 4)
    proj_gemm<<<g1, 256, 0, stream>>>(inputs, W_xh, b_h, out);
    rnn_scan<<<B_, NT2_, 0, stream>>>(W_hh, out);
}